// Round 1
// baseline (22.088 us; speedup 1.0000x reference)
//
#include <hip/hip_runtime.h>

// HiddenMerger: the masked softmax's diagonal is exactly 0 for rows m>=1
// (diagonal is masked with -2^32; exp underflows to 0 in fp32) and exactly
// 1/L for row 0 (all entries of row 0 round to exactly -2^32 in fp32 ->
// uniform softmax). So:
//   out[b,0,d]    = (1/L) * sum_l hidden[b,l,d]
//   out[b,m>=1,d] = 0
// Pure memory-bound: read 33.5 MB, write 33.5 MB.

namespace {
constexpr int B = 4;
constexpr int L = 2048;
constexpr int D = 1024;
constexpr int NCHUNK = 64;            // partial-sum chunks over L
constexpr int ROWS = L / NCHUNK;      // 32 rows per chunk
}

// Pass 1: partial column sums. grid (NCHUNK, B), block 256.
// Each block sums 32 rows of [D] via float4; partials staged into out rows 1..NCHUNK
// (those rows are zeroed later, so no d_ws needed).
__global__ void k_partial(const float* __restrict__ hidden, float* __restrict__ out) {
    const int b = blockIdx.y;
    const int c = blockIdx.x;
    const int t = threadIdx.x;  // 0..255, each handles 4 consecutive d via float4
    const float4* p =
        reinterpret_cast<const float4*>(hidden + ((size_t)b * L + (size_t)c * ROWS) * D) + t;
    float4 s = make_float4(0.f, 0.f, 0.f, 0.f);
#pragma unroll
    for (int i = 0; i < ROWS; ++i) {
        float4 v = p[(size_t)i * (D / 4)];
        s.x += v.x; s.y += v.y; s.z += v.z; s.w += v.w;
    }
    reinterpret_cast<float4*>(out + ((size_t)b * L + 1 + c) * D)[t] = s;
}

// Pass 2: reduce the NCHUNK partials (fixed order -> deterministic), scale by 1/L,
// write row 0. grid (B), block 256.
__global__ void k_finalize(float* __restrict__ out) {
    const int b = blockIdx.x;
    const int t = threadIdx.x;
    float4 s = make_float4(0.f, 0.f, 0.f, 0.f);
#pragma unroll
    for (int c = 0; c < NCHUNK; ++c) {
        float4 v = reinterpret_cast<const float4*>(out + ((size_t)b * L + 1 + c) * D)[t];
        s.x += v.x; s.y += v.y; s.z += v.z; s.w += v.w;
    }
    const float sc = 1.0f / (float)L;   // 2^-11, exact
    s.x *= sc; s.y *= sc; s.z *= sc; s.w *= sc;
    reinterpret_cast<float4*>(out + (size_t)b * L * D)[t] = s;
}

// Pass 3: zero rows 1..L-1 (also wipes the staged partials). grid (2047, B), block 256.
// (L-1)*D/4 = 2047*256 float4 stores per batch -> exact cover, no bounds check.
__global__ void k_zero(float* __restrict__ out) {
    const int b = blockIdx.y;
    const size_t i = (size_t)blockIdx.x * blockDim.x + threadIdx.x;
    reinterpret_cast<float4*>(out + ((size_t)b * L + 1) * D)[i] =
        make_float4(0.f, 0.f, 0.f, 0.f);
}

extern "C" void kernel_launch(void* const* d_in, const int* in_sizes, int n_in,
                              void* d_out, int out_size, void* d_ws, size_t ws_size,
                              hipStream_t stream) {
    const float* hidden = (const float*)d_in[0];
    float* out = (float*)d_out;

    hipLaunchKernelGGL(k_partial, dim3(NCHUNK, B), dim3(256), 0, stream, hidden, out);
    hipLaunchKernelGGL(k_finalize, dim3(B), dim3(256), 0, stream, out);
    hipLaunchKernelGGL(k_zero, dim3((L - 1) * D / 4 / 256, B), dim3(256), 0, stream, out);
}

// Round 3
// 14.750 us; speedup vs baseline: 1.4975x; 1.4975x over previous
//
#include <hip/hip_runtime.h>

// HiddenMerger: the masked softmax's diagonal is exactly 0 for rows m>=1
// (diagonal is masked with -2^32; exp underflows in fp32) and exactly 1/L
// for row 0 (every entry of row 0 rounds to exactly -2^32 -> uniform).
//   out[b,0,d]    = (1/L) * sum_l hidden[b,l,d]
//   out[b,m>=1,d] = 0
// Single dispatch, 256 blocks, role-split:
//   blocks 0..127  : sum block (c,b) owns an 8-float4 (128 B) column slice of
//                    batch b, sums it over all L rows (no cross-block reduce),
//                    writes its 128 B of row 0 scaled by 1/L.
//   blocks 128..255: zero block, fills 64 rows of out with 0 (row 0 skipped).
// Traffic: 33.5 MB read + 33.5 MB write, every line touched exactly once.

namespace {
constexpr int B = 4;
constexpr int L = 2048;
constexpr int D = 1024;
constexpr int D4 = D / 4;            // 256 float4 per row
constexpr int CI = 8;                // float4 columns per sum block (128 B)
constexpr int CHUNKS = D4 / CI;      // 32 column slices per batch
constexpr int WAYS = 256 / CI;       // 32 row-ways per sum block
constexpr int NSUM = CHUNKS * B;     // 128 sum blocks
constexpr int ZBLK = 128;            // zero blocks
constexpr int ZROWS = L / (ZBLK / B);// 64 rows zeroed per zero block
}

__global__ __launch_bounds__(256) void k_fused(const float* __restrict__ hidden,
                                               float* __restrict__ out) {
    const int bid = blockIdx.x;
    const int t = threadIdx.x;

    if (bid < NSUM) {
        // ---- sum role ----
        const int c = bid & (CHUNKS - 1);   // column slice 0..31
        const int b = bid >> 5;             // batch 0..3
        const int ci = t & (CI - 1);        // float4 column within slice
        const int ri = t >> 3;              // row-way 0..31
        const int colf4 = c * CI + ci;      // 0..255, in range

        const float4* hp = reinterpret_cast<const float4*>(hidden + (size_t)b * L * D);
        float4 s = make_float4(0.f, 0.f, 0.f, 0.f);
#pragma unroll 8
        for (int r = ri; r < L; r += WAYS) {            // 64 iterations
            float4 v = hp[(size_t)r * D4 + colf4];
            s.x += v.x; s.y += v.y; s.z += v.z; s.w += v.w;
        }

        __shared__ float4 red[256];
        red[t] = s;
        __syncthreads();
#pragma unroll
        for (int sh = WAYS / 2; sh > 0; sh >>= 1) {     // 32 -> 1, fixed order
            if (ri < sh) {
                float4 o = red[(ri + sh) * CI + ci];
                float4 m = red[t];
                m.x += o.x; m.y += o.y; m.z += o.z; m.w += o.w;
                red[t] = m;
            }
            __syncthreads();
        }
        if (ri == 0) {
            float4 m = red[ci];
            const float sc = 1.0f / (float)L;           // 2^-11, exact
            m.x *= sc; m.y *= sc; m.z *= sc; m.w *= sc;
            reinterpret_cast<float4*>(out + (size_t)b * L * D)[colf4] = m;
        }
    } else {
        // ---- zero role ----
        const int z = bid - NSUM;           // 0..127
        const int zb = z >> 5;              // batch 0..3
        const int zc = z & 31;              // row group 0..31
        float4* op = reinterpret_cast<float4*>(out + (size_t)zb * L * D);
        const int r0 = zc * ZROWS;
        const float4 zero = make_float4(0.f, 0.f, 0.f, 0.f);
#pragma unroll 4
        for (int i = 0; i < ZROWS; ++i) {
            const int row = r0 + i;
            if (row > 0)                    // row 0 belongs to the sum blocks
                op[(size_t)row * D4 + t] = zero;
        }
    }
}

extern "C" void kernel_launch(void* const* d_in, const int* in_sizes, int n_in,
                              void* d_out, int out_size, void* d_ws, size_t ws_size,
                              hipStream_t stream) {
    const float* hidden = (const float*)d_in[0];
    float* out = (float*)d_out;
    hipLaunchKernelGGL(k_fused, dim3(NSUM + ZBLK), dim3(256), 0, stream, hidden, out);
}